// Round 10
// baseline (839.930 us; speedup 1.0000x reference)
//
#include <hip/hip_runtime.h>
#include <math.h>

#define BB  256
#define TT  2048
#define VV  64
#define DD  50
#define HH  50
#define HIDN 100

// [tok][j] = seqFMA_d(embed[tok][d]*Wx[d][j]) + b_rnn[j]; cols 50..63 = 0.
__device__ float g_emWxb[VV * 64];

// ---------------------------------------------------------------------------
// XLA/Eigen fast-tanh, FMA-contracted Horner. BIT-EXACT with the reference
// trajectory (R6-R9 pass, absmax 0.015625). Do not touch: clamp
// +-7.90531110763549805, fmaf Horner, IEEE f32 divide, |x|<4e-4 passthrough.
// ---------------------------------------------------------------------------
__device__ __forceinline__ float xla_tanhf_fma(float x) {
#pragma clang fp contract(off)
  float ax = fabsf(x);
  float cx = fminf(fmaxf(x, -7.90531110763549805f), 7.90531110763549805f);
  float x2 = cx * cx;
  float p = -2.76076847742355e-16f;
  p = fmaf(x2, p, 2.00018790482477e-13f);
  p = fmaf(x2, p, -8.60467152213735e-11f);
  p = fmaf(x2, p, 5.12229709037114e-08f);
  p = fmaf(x2, p, 1.48572235717979e-05f);
  p = fmaf(x2, p, 6.37261928875436e-04f);
  p = fmaf(x2, p, 4.89352455891786e-03f);
  p = cx * p;
  float q = 1.19825839466702e-06f;
  q = fmaf(x2, q, 1.18534705686654e-04f);
  q = fmaf(x2, q, 2.26843463243900e-03f);
  q = fmaf(x2, q, 4.89352518554385e-03f);
  float r = p / q;
  return (ax < 0.0004f) ? x : r;
}

// ---------------------------------------------------------------------------
// K1: xp table, Eigen-gemm bit-emulation (unchanged from passing R6).
// ---------------------------------------------------------------------------
__global__ __launch_bounds__(256) void prep_kernel(
    const float* __restrict__ embed, const float* __restrict__ Wx,
    const float* __restrict__ b_rnn) {
#pragma clang fp contract(off)
  int o = blockIdx.x * 256 + threadIdx.x;
  if (o >= VV * 64) return;
  int v = o >> 6, j = o & 63;
  float val = 0.f;
  if (j < HH) {
    float s = 0.f;
    for (int d = 0; d < DD; ++d)
      s = fmaf(embed[v * DD + d], Wx[d * HH + j], s);
    val = s + b_rnn[j];
  }
  g_emWxb[o] = val;
}

// ---------------------------------------------------------------------------
// K2: recurrence with ds_bpermute broadcast.
// Evolution: LDS+barrier (R6, 680cyc/step: barrier drains vmcnt -> store wait
// every step) -> interleaved readlane (R8, 1080: SGPR hazard/pair) -> batched
// readlane (R9, 737: broadcast serialized ahead of chain, VALU issue).
// ds_bpermute fixes all three: reads live VGPR h (no publish, no barrier, no
// store drain), returns into VGPRs (no SGPR hazard), issues on the DS pipe
// (doesn't consume VALU issue slots; in-order returns ~4cyc/op rate-match
// the 4cyc/FMA chain). Bits exact: bpermute returns source-lane bits.
// Chain arithmetic bit-identical: 50x fmaf ascending i, single accumulator;
// pre = xp + acc; xla_tanhf_fma. Order is load-bearing (chaos ~1.3e7 gain).
// Lanes >= 50: whcol=0, xp=0 -> h=0 -> hs cols 50..63 = 0.
// ---------------------------------------------------------------------------
__global__ __launch_bounds__(64) void rnn_kernel(
    const int* __restrict__ inputs, const float* __restrict__ Wh,
    float* hs) {
#pragma clang fp contract(off)
  const int b = blockIdx.x;
  const int lane = threadIdx.x;

  __shared__ __align__(16) float emw[VV * 64];  // 16 KB
  __shared__ int toks[TT];                      // 8 KB

  for (int o = lane; o < VV * 64; o += 64) emw[o] = g_emWxb[o];
  const int* rowp = inputs + (size_t)b * TT;
  for (int t = lane; t < TT; t += 64) toks[t] = rowp[t];

  float whcol[HH];
#pragma unroll
  for (int i = 0; i < HH; ++i)
    whcol[i] = (lane < HH) ? Wh[i * HH + lane] : 0.f;
  __syncthreads();

  float* outp = hs + (size_t)b * TT * 64;
  float h = 0.f;
  float xp = emw[toks[0] * 64 + lane];

  for (int t = 0; t < TT; ++t) {
    // ---- broadcast phase: 50 ds_bpermute (DS pipe, VGPR results) ----
    float hv[HH];
#pragma unroll
    for (int i = 0; i < HH; ++i)
      hv[i] = __int_as_float(
          __builtin_amdgcn_ds_bpermute(i * 4, __float_as_int(h)));
    __builtin_amdgcn_sched_barrier(0);   // don't sink bpermutes into the chain

    // ---- pure FMA chain; hv_i returns (in-order DS) pace the chain ----
    float acc = 0.f;
#pragma unroll
    for (int i = 0; i < HH; ++i)
      acc = fmaf(hv[i], whcol[i], acc);
    float pre = xp + acc;

    // prefetch next xp (independent of h; overlaps tanh)
    int tn = toks[(t + 1 < TT) ? (t + 1) : (TT - 1)];
    float xpn = emw[tn * 64 + lane];

    h = xla_tanhf_fma(pre);
    outp[(size_t)t * 64 + lane] = h;   // coalesced fire-and-forget (no barrier -> never drained)
    xp = xpn;
  }
}

// ---------------------------------------------------------------------------
// K3: MLP head — UNCHANGED from R9 (isolate the rnn variable this round).
// One THREAD per (b,t) row, 4-way c-unroll, per-element chains bit-identical
// to R6 (absmax must stay exactly 0.015625). hs/out may alias -> NO restrict.
// ---------------------------------------------------------------------------
__global__ __launch_bounds__(256) void head_kernel(
    const float* hs, const float* __restrict__ W1,
    const float* __restrict__ b1, const float* __restrict__ W2,
    const float* __restrict__ b2, float* out) {
#pragma clang fp contract(off)
  const int r = blockIdx.x * 256 + threadIdx.x;  // 0 .. B*T-1
  const float* hrow = hs + (size_t)r * 64;

  float h[52];
#pragma unroll
  for (int q = 0; q < 13; ++q) {     // hrow is 256B-aligned
    float4 v = *reinterpret_cast<const float4*>(hrow + 4 * q);
    h[4 * q + 0] = v.x;
    h[4 * q + 1] = v.y;
    h[4 * q + 2] = v.z;
    h[4 * q + 3] = v.w;
  }

  float logit[VV];
#pragma unroll
  for (int jj = 0; jj < VV; ++jj) logit[jj] = b2[jj];

  for (int c = 0; c < HIDN; c += 4) {   // 25 iterations
    float a0 = 0.f, a1 = 0.f, a2 = 0.f, a3 = 0.f;
#pragma unroll
    for (int i = 0; i < HH; ++i) {      // 4 independent chains, same per-chain order
      const float* w1r = W1 + i * HIDN + c;
      a0 = fmaf(h[i], w1r[0], a0);
      a1 = fmaf(h[i], w1r[1], a1);
      a2 = fmaf(h[i], w1r[2], a2);
      a3 = fmaf(h[i], w1r[3], a3);
    }
    a0 += b1[c + 0]; a0 = fmaxf(a0, 0.f);
    a1 += b1[c + 1]; a1 = fmaxf(a1, 0.f);
    a2 += b1[c + 2]; a2 = fmaxf(a2, 0.f);
    a3 += b1[c + 3]; a3 = fmaxf(a3, 0.f);
    const float* v0 = W2 + (c + 0) * VV;
    const float* v1 = W2 + (c + 1) * VV;
    const float* v2 = W2 + (c + 2) * VV;
    const float* v3 = W2 + (c + 3) * VV;
    // logit[jj] updated in ascending-c order (c, c+1, c+2, c+3) = R6 order
#pragma unroll
    for (int jj = 0; jj < VV; ++jj) {
      float acc = logit[jj];
      acc = fmaf(a0, v0[jj], acc);
      acc = fmaf(a1, v1[jj], acc);
      acc = fmaf(a2, v2[jj], acc);
      acc = fmaf(a3, v3[jj], acc);
      logit[jj] = acc;
    }
  }

  float* orow = out + (size_t)r * 64;
#pragma unroll
  for (int q = 0; q < 16; ++q) {
    float4 v;
    v.x = logit[4 * q + 0];
    v.y = logit[4 * q + 1];
    v.z = logit[4 * q + 2];
    v.w = logit[4 * q + 3];
    *reinterpret_cast<float4*>(orow + 4 * q) = v;
  }
}

// ---------------------------------------------------------------------------
extern "C" void kernel_launch(void* const* d_in, const int* in_sizes, int n_in,
                              void* d_out, int out_size, void* d_ws, size_t ws_size,
                              hipStream_t stream) {
  // Map inputs by element-count signature (dict order breaks the Wx/Wh tie).
  const void* p[9] = {nullptr};
  const int want[9] = {BB * TT, VV * DD, DD * HH, HH * HH, HH,
                       HH * HIDN, HIDN, HIDN * VV, VV};
  bool used[32] = {false};
  for (int k = 0; k < 9; ++k)
    for (int i = 0; i < n_in && i < 32; ++i)
      if (!used[i] && in_sizes[i] == want[k]) { p[k] = d_in[i]; used[i] = true; break; }

  const int*   inputs = (const int*)  p[0];
  const float* embed  = (const float*)p[1];
  const float* Wx     = (const float*)p[2];
  const float* Wh     = (const float*)p[3];
  const float* b_rnn  = (const float*)p[4];
  const float* W1     = (const float*)p[5];
  const float* b1     = (const float*)p[6];
  const float* W2     = (const float*)p[7];
  const float* b2     = (const float*)p[8];

  float* out = (float*)d_out;
  float* hs = (ws_size >= (size_t)(BB * TT * 64) * sizeof(float))
                  ? (float*)d_ws : out;

  prep_kernel<<<(VV * 64 + 255) / 256, 256, 0, stream>>>(embed, Wx, b_rnn);
  rnn_kernel<<<BB, 64, 0, stream>>>(inputs, Wh, hs);
  head_kernel<<<(BB * TT) / 256, 256, 0, stream>>>(hs, W1, b1, W2, b2, out);
}

// Round 11
// 744.214 us; speedup vs baseline: 1.1286x; 1.1286x over previous
//
#include <hip/hip_runtime.h>
#include <math.h>

#define BB  256
#define TT  2048
#define VV  64
#define DD  50
#define HH  50
#define HIDN 100

// [tok][j] = seqFMA_d(embed[tok][d]*Wx[d][j]) + b_rnn[j]; cols 50..63 = 0.
__device__ float g_emWxb[VV * 64];

// ---------------------------------------------------------------------------
// XLA/Eigen fast-tanh, FMA-contracted Horner. BIT-EXACT with the reference
// trajectory (R6-R10 pass, absmax 0.015625). Do not touch: clamp
// +-7.90531110763549805, fmaf Horner, IEEE f32 divide, |x|<4e-4 passthrough.
// ---------------------------------------------------------------------------
__device__ __forceinline__ float xla_tanhf_fma(float x) {
#pragma clang fp contract(off)
  float ax = fabsf(x);
  float cx = fminf(fmaxf(x, -7.90531110763549805f), 7.90531110763549805f);
  float x2 = cx * cx;
  float p = -2.76076847742355e-16f;
  p = fmaf(x2, p, 2.00018790482477e-13f);
  p = fmaf(x2, p, -8.60467152213735e-11f);
  p = fmaf(x2, p, 5.12229709037114e-08f);
  p = fmaf(x2, p, 1.48572235717979e-05f);
  p = fmaf(x2, p, 6.37261928875436e-04f);
  p = fmaf(x2, p, 4.89352455891786e-03f);
  p = cx * p;
  float q = 1.19825839466702e-06f;
  q = fmaf(x2, q, 1.18534705686654e-04f);
  q = fmaf(x2, q, 2.26843463243900e-03f);
  q = fmaf(x2, q, 4.89352518554385e-03f);
  float r = p / q;
  return (ax < 0.0004f) ? x : r;
}

// ---------------------------------------------------------------------------
// K1: xp table, Eigen-gemm bit-emulation (unchanged from passing R6).
// ---------------------------------------------------------------------------
__global__ __launch_bounds__(256) void prep_kernel(
    const float* __restrict__ embed, const float* __restrict__ Wx,
    const float* __restrict__ b_rnn) {
#pragma clang fp contract(off)
  int o = blockIdx.x * 256 + threadIdx.x;
  if (o >= VV * 64) return;
  int v = o >> 6, j = o & 63;
  float val = 0.f;
  if (j < HH) {
    float s = 0.f;
    for (int d = 0; d < DD; ++d)
      s = fmaf(embed[v * DD + d], Wx[d * HH + j], s);
    val = s + b_rnn[j];
  }
  g_emWxb[o] = val;
}

// ---------------------------------------------------------------------------
// K2: recurrence, BARRIER-FREE LDS broadcast.
// Broadcast-cost ladder: LDS+syncthreads (R6, 680cyc/step: barrier drains
// vmcnt -> waits the fire-and-forget store) -> 50 readlanes (R9, 737: 50
// serialized ops; SGPR hazards) -> 50 bpermutes (R10, 737: identical — 50
// in-flight DS ops saturate the 4-bit lgkmcnt, chain can't start early).
// Fix: ds_write_b32 h + 13 uniform ds_read_b128 = 14 DS ops (< lgkmcnt 15
// ceiling -> compiler emits fine-grained waits); b128 returns (~12cyc/4
// floats) outpace the 4cyc/FMA chain. Single wave per block -> NO barrier
// needed for same-wave LDS RAW (in-order DS + auto lgkmcnt), so the HBM
// store is never drained in-loop.
// Chain arithmetic bit-identical: 50x fmaf ascending i, single accumulator;
// pre = xp + acc; xla_tanhf_fma. Order is load-bearing (chaos ~1.3e7 gain).
// Lanes >= 50: whcol=0, xp=0 -> h=0 -> hs cols 50..63 = 0.
// ---------------------------------------------------------------------------
__global__ __launch_bounds__(64) void rnn_kernel(
    const int* __restrict__ inputs, const float* __restrict__ Wh,
    float* hs) {
#pragma clang fp contract(off)
  const int b = blockIdx.x;
  const int lane = threadIdx.x;

  __shared__ __align__(16) float emw[VV * 64];  // 16 KB
  __shared__ int toks[TT];                      // 8 KB
  __shared__ __align__(16) float hshare[64];    // h broadcast buffer

  for (int o = lane; o < VV * 64; o += 64) emw[o] = g_emWxb[o];
  const int* rowp = inputs + (size_t)b * TT;
  for (int t = lane; t < TT; t += 64) toks[t] = rowp[t];

  float whcol[HH];
#pragma unroll
  for (int i = 0; i < HH; ++i)
    whcol[i] = (lane < HH) ? Wh[i * HH + lane] : 0.f;

  hshare[lane] = 0.f;   // h(0) = 0
  __syncthreads();      // once, for emw/toks (multi... single wave: cheap, safe)

  float* outp = hs + (size_t)b * TT * 64;
  float h = 0.f;
  float xp = emw[toks[0] * 64 + lane];

  const float4* hp = reinterpret_cast<const float4*>(hshare);

  for (int t = 0; t < TT; ++t) {
    // ---- broadcast: 13 uniform ds_read_b128 (52 floats, use 50) ----
    float4 hq[13];
#pragma unroll
    for (int q = 0; q < 13; ++q) hq[q] = hp[q];

    // ---- pure FMA chain, ascending i, single accumulator ----
    float acc = 0.f;
#pragma unroll
    for (int q = 0; q < 12; ++q) {
      acc = fmaf(hq[q].x, whcol[4 * q + 0], acc);
      acc = fmaf(hq[q].y, whcol[4 * q + 1], acc);
      acc = fmaf(hq[q].z, whcol[4 * q + 2], acc);
      acc = fmaf(hq[q].w, whcol[4 * q + 3], acc);
    }
    acc = fmaf(hq[12].x, whcol[48], acc);
    acc = fmaf(hq[12].y, whcol[49], acc);
    float pre = xp + acc;

    // prefetch next xp (independent of h; overlaps tanh)
    int tn = toks[(t + 1 < TT) ? (t + 1) : (TT - 1)];
    float xpn = emw[tn * 64 + lane];

    h = xla_tanhf_fma(pre);
    hshare[lane] = h;                  // publish for next step (same-wave RAW)
    outp[(size_t)t * 64 + lane] = h;   // coalesced fire-and-forget (never drained)
    xp = xpn;
  }
}

// ---------------------------------------------------------------------------
// K3: MLP head — UNCHANGED from R9/R10 (isolate the rnn variable).
// Per-element chains bit-identical to R6 (absmax must stay exactly
// 0.015625). hs/out may alias -> NO restrict.
// ---------------------------------------------------------------------------
__global__ __launch_bounds__(256) void head_kernel(
    const float* hs, const float* __restrict__ W1,
    const float* __restrict__ b1, const float* __restrict__ W2,
    const float* __restrict__ b2, float* out) {
#pragma clang fp contract(off)
  const int r = blockIdx.x * 256 + threadIdx.x;  // 0 .. B*T-1
  const float* hrow = hs + (size_t)r * 64;

  float h[52];
#pragma unroll
  for (int q = 0; q < 13; ++q) {     // hrow is 256B-aligned
    float4 v = *reinterpret_cast<const float4*>(hrow + 4 * q);
    h[4 * q + 0] = v.x;
    h[4 * q + 1] = v.y;
    h[4 * q + 2] = v.z;
    h[4 * q + 3] = v.w;
  }

  float logit[VV];
#pragma unroll
  for (int jj = 0; jj < VV; ++jj) logit[jj] = b2[jj];

  for (int c = 0; c < HIDN; c += 4) {   // 25 iterations
    float a0 = 0.f, a1 = 0.f, a2 = 0.f, a3 = 0.f;
#pragma unroll
    for (int i = 0; i < HH; ++i) {      // 4 independent chains, same per-chain order
      const float* w1r = W1 + i * HIDN + c;
      a0 = fmaf(h[i], w1r[0], a0);
      a1 = fmaf(h[i], w1r[1], a1);
      a2 = fmaf(h[i], w1r[2], a2);
      a3 = fmaf(h[i], w1r[3], a3);
    }
    a0 += b1[c + 0]; a0 = fmaxf(a0, 0.f);
    a1 += b1[c + 1]; a1 = fmaxf(a1, 0.f);
    a2 += b1[c + 2]; a2 = fmaxf(a2, 0.f);
    a3 += b1[c + 3]; a3 = fmaxf(a3, 0.f);
    const float* v0 = W2 + (c + 0) * VV;
    const float* v1 = W2 + (c + 1) * VV;
    const float* v2 = W2 + (c + 2) * VV;
    const float* v3 = W2 + (c + 3) * VV;
    // logit[jj] updated in ascending-c order (c, c+1, c+2, c+3) = R6 order
#pragma unroll
    for (int jj = 0; jj < VV; ++jj) {
      float acc = logit[jj];
      acc = fmaf(a0, v0[jj], acc);
      acc = fmaf(a1, v1[jj], acc);
      acc = fmaf(a2, v2[jj], acc);
      acc = fmaf(a3, v3[jj], acc);
      logit[jj] = acc;
    }
  }

  float* orow = out + (size_t)r * 64;
#pragma unroll
  for (int q = 0; q < 16; ++q) {
    float4 v;
    v.x = logit[4 * q + 0];
    v.y = logit[4 * q + 1];
    v.z = logit[4 * q + 2];
    v.w = logit[4 * q + 3];
    *reinterpret_cast<float4*>(orow + 4 * q) = v;
  }
}

// ---------------------------------------------------------------------------
extern "C" void kernel_launch(void* const* d_in, const int* in_sizes, int n_in,
                              void* d_out, int out_size, void* d_ws, size_t ws_size,
                              hipStream_t stream) {
  // Map inputs by element-count signature (dict order breaks the Wx/Wh tie).
  const void* p[9] = {nullptr};
  const int want[9] = {BB * TT, VV * DD, DD * HH, HH * HH, HH,
                       HH * HIDN, HIDN, HIDN * VV, VV};
  bool used[32] = {false};
  for (int k = 0; k < 9; ++k)
    for (int i = 0; i < n_in && i < 32; ++i)
      if (!used[i] && in_sizes[i] == want[k]) { p[k] = d_in[i]; used[i] = true; break; }

  const int*   inputs = (const int*)  p[0];
  const float* embed  = (const float*)p[1];
  const float* Wx     = (const float*)p[2];
  const float* Wh     = (const float*)p[3];
  const float* b_rnn  = (const float*)p[4];
  const float* W1     = (const float*)p[5];
  const float* b1     = (const float*)p[6];
  const float* W2     = (const float*)p[7];
  const float* b2     = (const float*)p[8];

  float* out = (float*)d_out;
  float* hs = (ws_size >= (size_t)(BB * TT * 64) * sizeof(float))
                  ? (float*)d_ws : out;

  prep_kernel<<<(VV * 64 + 255) / 256, 256, 0, stream>>>(embed, Wx, b_rnn);
  rnn_kernel<<<BB, 64, 0, stream>>>(inputs, Wh, hs);
  head_kernel<<<(BB * TT) / 256, 256, 0, stream>>>(hs, W1, b1, W2, b2, out);
}